// Round 7
// baseline (804.260 us; speedup 1.0000x reference)
//
#include <hip/hip_runtime.h>
#include <hip/hip_bf16.h>

namespace {
constexpr int Bn = 512;
constexpr int Ln = 1024;
constexpr int Vn = 64;
constexpr int En = 128;
constexpr int Kc = Vn + En;              // 192
constexpr int HP = 136;                  // fp32 fallback kernel only
constexpr int WS_FLOATS = En * Kc + En;
constexpr size_t SEQB_BYTES  = (size_t)Bn * Ln * Vn * 2;  // 67,108,864
constexpr size_t WALLB_BYTES = (size_t)En * Kc * 2;       // 49,152
constexpr size_t BC_BYTES    = En * 4;                    // 512
constexpr size_t WOUTP_BYTES = (size_t)Vn * En * 2;       // 16,384
constexpr size_t FAST_WS  = SEQB_BYTES + WALLB_BYTES + BC_BYTES;               // round-6 path
constexpr size_t FAST_WS2 = SEQB_BYTES + WALLB_BYTES + BC_BYTES + WOUTP_BYTES; // register path
}

typedef __attribute__((ext_vector_type(8))) short bf16x8;
typedef __attribute__((ext_vector_type(4))) float f32x4;
typedef __attribute__((ext_vector_type(8))) unsigned short u16x8;

__device__ __forceinline__ unsigned f2b(float f) {
  unsigned u = __float_as_uint(f);
  u += 0x7fffu + ((u >> 16) & 1u);
  return u >> 16;
}
__device__ __forceinline__ float b2f(unsigned short b) {
  return __uint_as_float(((unsigned)b) << 16);
}
__device__ __forceinline__ bf16x8 pack8(const float* v) {
  bf16x8 r;
#pragma unroll
  for (int i = 0; i < 8; ++i) r[i] = (short)f2b(v[i]);
  return r;
}

// column permutation for the in-register h cycle:
// cm(32*kt + 8*lg + 4*hi + i) = 16*(4*hi + kt) + 4*lg + i
__device__ __forceinline__ int cm(int kh) {
  const int kt = (kh >> 5) & 3, lg = (kh >> 3) & 3, hi = (kh >> 2) & 1, i = kh & 3;
  return 16 * (4 * hi + kt) + 4 * lg + i;
}

#define MFMA __builtin_amdgcn_mfma_f32_16x16x32_bf16

// ---------------- register-resident fast path ----------------

// seq fp32 -> bf16 (bulk, memory-bound)
__global__ void seq_cvt(const float* __restrict__ seq, unsigned short* __restrict__ seqb) {
  const size_t n = (size_t)Bn * Ln * Vn;
  size_t i = ((size_t)blockIdx.x * blockDim.x + threadIdx.x) * 8;
  const size_t stride = (size_t)gridDim.x * blockDim.x * 8;
  for (; i < n; i += stride) {
    const f32x4 a = *(const f32x4*)(seq + i);
    const f32x4 b = *(const f32x4*)(seq + i + 4);
    u16x8 o;
#pragma unroll
    for (int j = 0; j < 4; ++j) o[j] = (unsigned short)f2b(a[j]);
#pragma unroll
    for (int j = 0; j < 4; ++j) o[4 + j] = (unsigned short)f2b(b[j]);
    *(u16x8*)(seqb + i) = o;
  }
}

// Wall2[j][k] bf16: k<64 -> folded input proj; k>=64 -> Whh[j][cm(k-64)] (h-cols permuted)
// bc[j] f32 = b_h[j] + sum_e b_in[e]*W_h[j][e]
__global__ void rnn_setup2(const float* __restrict__ W_in, const float* __restrict__ b_in,
                           const float* __restrict__ W_h, const float* __restrict__ b_h,
                           unsigned short* __restrict__ wall2, float* __restrict__ bc) {
  const int j = blockIdx.x;    // 0..127
  const int k = threadIdx.x;   // 0..191
  const float* whr = W_h + j * (2 * En);
  float s;
  if (k < Vn) {
    s = 0.f;
#pragma unroll 8
    for (int e = 0; e < En; ++e) s = fmaf(W_in[e * Vn + k], whr[e], s);
  } else {
    s = whr[En + cm(k - Vn)];
  }
  wall2[j * Kc + k] = (unsigned short)f2b(s);
  if (k == 0) {
    float b = b_h[j];
    for (int e = 0; e < En; ++e) b = fmaf(b_in[e], whr[e], b);
    bc[j] = b;
  }
}

// woutp[v][kk] = W_out[v][cm(kk)] (bf16) — epilogue A-operand with matching col permutation
__global__ void wout_setup(const float* __restrict__ W_out, unsigned short* __restrict__ woutp) {
  const int v = blockIdx.x;    // 0..63
  const int kk = threadIdx.x;  // 0..127
  woutp[v * En + kk] = (unsigned short)f2b(W_out[(size_t)v * En + cm(kk)]);
}

// One wave per 16 batch rows. h lives ONLY in registers: the D fragment of step t
// (col=batch,row=j) IS the B fragment of step t+1 (col=batch,k) after relu+cvt_pk,
// thanks to the cm() column permutation baked into Wall2/woutp. No LDS, no barrier.
__global__ __launch_bounds__(64, 1) void rnn_reg(
    const unsigned short* __restrict__ seqb, const unsigned short* __restrict__ wall2,
    const float* __restrict__ bc, const unsigned short* __restrict__ woutp,
    const float* __restrict__ b_out, float* __restrict__ out) {
  const int l   = threadIdx.x & 63;
  const int l15 = l & 15;
  const int lg  = l >> 4;
  const int r0  = blockIdx.x * 16;

  // weights: 8 n-tiles x 6 k-tiles, 192 VGPRs, loaded once
  bf16x8 Aw[8][6];
#pragma unroll
  for (int nn = 0; nn < 8; ++nn) {
    const unsigned short* p = wall2 + (size_t)(16 * nn + l15) * Kc + lg * 8;
#pragma unroll
    for (int kt = 0; kt < 6; ++kt) Aw[nn][kt] = *(const bf16x8*)(p + kt * 32);
  }
  f32x4 bcv[8];
#pragma unroll
  for (int nn = 0; nn < 8; ++nn) bcv[nn] = *(const f32x4*)(bc + 16 * nn + 4 * lg);

  const unsigned short* sqb = seqb + ((size_t)(r0 + l15) * Ln) * Vn + lg * 8;
  bf16x8 sreg[4][2];
  bf16x8 zA[4], zB[4];
#pragma unroll
  for (int kt = 0; kt < 4; ++kt) {
#pragma unroll
    for (int i = 0; i < 8; ++i) { zA[kt][i] = 0; zB[kt][i] = 0; }
  }

#define SEQ_PF(BI, T)                                                \
  { const int tp = ((T) < Ln) ? (T) : (Ln - 1);                      \
    const bf16x8* sp = (const bf16x8*)(sqb + (size_t)tp * Vn);       \
    sreg[BI][0] = sp[0];                                             \
    sreg[BI][1] = sp[4]; }

  SEQ_PF(0, 0)
  SEQ_PF(1, 1)
  SEQ_PF(2, 2)

  // z[kt] elems = [acc[kt][0..3] , acc[kt+4][0..3]] after relu, packed to bf16
#define PACK_Z(DST, PA, PB)                                                    \
  {                                                                            \
    const float x0 = fmaxf((PA)[0], 0.f), x1 = fmaxf((PA)[1], 0.f);            \
    const float x2 = fmaxf((PA)[2], 0.f), x3 = fmaxf((PA)[3], 0.f);            \
    const float y0 = fmaxf((PB)[0], 0.f), y1 = fmaxf((PB)[1], 0.f);            \
    const float y2 = fmaxf((PB)[2], 0.f), y3 = fmaxf((PB)[3], 0.f);            \
    unsigned u0, u1, u2, u3;                                                   \
    asm("v_cvt_pk_bf16_f32 %0, %1, %2" : "=v"(u0) : "v"(x0), "v"(x1));         \
    asm("v_cvt_pk_bf16_f32 %0, %1, %2" : "=v"(u1) : "v"(x2), "v"(x3));         \
    asm("v_cvt_pk_bf16_f32 %0, %1, %2" : "=v"(u2) : "v"(y0), "v"(y1));         \
    asm("v_cvt_pk_bf16_f32 %0, %1, %2" : "=v"(u3) : "v"(y2), "v"(y3));         \
    union { unsigned u[4]; bf16x8 v; } c_;                                     \
    c_.u[0] = u0; c_.u[1] = u1; c_.u[2] = u2; c_.u[3] = u3;                    \
    DST = c_.v;                                                                \
  }

#define STEP(P, ZC, ZN)                                                        \
  {                                                                            \
    SEQ_PF(((P) + 3) & 3, t + (P) + 3);                                        \
    const bf16x8 s0 = sreg[(P)][0], s1 = sreg[(P)][1];                         \
    f32x4 acc[8];                                                              \
    _Pragma("unroll") for (int nn = 0; nn < 8; ++nn)                           \
        acc[nn] = MFMA(Aw[nn][0], s0, bcv[nn], 0, 0, 0);                       \
    _Pragma("unroll") for (int nn = 0; nn < 8; ++nn)                           \
        acc[nn] = MFMA(Aw[nn][1], s1, acc[nn], 0, 0, 0);                       \
    _Pragma("unroll") for (int nn = 0; nn < 8; ++nn)                           \
        acc[nn] = MFMA(Aw[nn][2], ZC[0], acc[nn], 0, 0, 0);                    \
    _Pragma("unroll") for (int nn = 0; nn < 8; ++nn)                           \
        acc[nn] = MFMA(Aw[nn][3], ZC[1], acc[nn], 0, 0, 0);                    \
    _Pragma("unroll") for (int nn = 0; nn < 8; ++nn)                           \
        acc[nn] = MFMA(Aw[nn][4], ZC[2], acc[nn], 0, 0, 0);                    \
    _Pragma("unroll") for (int nn = 0; nn < 8; ++nn)                           \
        acc[nn] = MFMA(Aw[nn][5], ZC[3], acc[nn], 0, 0, 0);                    \
    PACK_Z(ZN[0], acc[0], acc[4]);                                             \
    PACK_Z(ZN[1], acc[1], acc[5]);                                             \
    PACK_Z(ZN[2], acc[2], acc[6]);                                             \
    PACK_Z(ZN[3], acc[3], acc[7]);                                             \
  }

#pragma unroll 1
  for (int t = 0; t < Ln; t += 4) {
    STEP(0, zA, zB)
    STEP(1, zB, zA)
    STEP(2, zA, zB)
    STEP(3, zB, zA)
  }
#undef STEP
#undef SEQ_PF

  // epilogue: out = h @ W_out^T + b_out ; h_final frags in zA (permuted space = woutp cols)
#pragma unroll
  for (int mt = 0; mt < 4; ++mt) {
    f32x4 o = *(const f32x4*)(b_out + 16 * mt + 4 * lg);
#pragma unroll
    for (int kt = 0; kt < 4; ++kt) {
      const bf16x8 wv =
          *(const bf16x8*)(woutp + (size_t)(16 * mt + l15) * En + kt * 32 + lg * 8);
      o = MFMA(wv, zA[kt], o, 0, 0, 0);
    }
    *(f32x4*)&out[(size_t)(r0 + l15) * Vn + 16 * mt + 4 * lg] = o;
  }
}

// ---------------- round-6 LDS fast path (fallback #1) ----------------

__global__ void rnn_setup_bf(const float* __restrict__ W_in, const float* __restrict__ b_in,
                             const float* __restrict__ W_h, const float* __restrict__ b_h,
                             unsigned short* __restrict__ wallb, float* __restrict__ bc) {
  const int j = blockIdx.x;
  const int k = threadIdx.x;
  const float* whr = W_h + j * (2 * En);
  float s;
  if (k < Vn) {
    s = 0.f;
#pragma unroll 8
    for (int e = 0; e < En; ++e) s = fmaf(W_in[e * Vn + k], whr[e], s);
  } else {
    s = whr[Vn + k];
  }
  wallb[j * Kc + k] = (unsigned short)f2b(s);
  if (k == 0) {
    float b = b_h[j];
    for (int e = 0; e < En; ++e) b = fmaf(b_in[e], whr[e], b);
    bc[j] = b;
  }
}

__global__ __launch_bounds__(128, 1) void rnn_fast2(
    const unsigned short* __restrict__ seqb, const unsigned short* __restrict__ wallb,
    const float* __restrict__ bc, const float* __restrict__ W_out,
    const float* __restrict__ b_out, float* __restrict__ out) {
  __shared__ __align__(16) unsigned char hbB[2][4096];

  const int tid = threadIdx.x;
  const int w   = tid >> 6;
  const int l   = tid & 63;
  const int l15 = l & 15;
  const int lg  = l >> 4;
  const int r0  = blockIdx.x * 16;
  const int swz = (l15 & 7) << 4;

  bf16x8 Aw[4][6];
  f32x4 bcv[4];
#pragma unroll
  for (int nn = 0; nn < 4; ++nn) {
    const int n = 4 * w + nn;
    const unsigned short* p = wallb + (size_t)(16 * n + l15) * Kc + lg * 8;
#pragma unroll
    for (int kt = 0; kt < 6; ++kt) Aw[nn][kt] = *(const bf16x8*)(p + kt * 32);
    bcv[nn] = *(const f32x4*)(bc + 16 * n + 4 * lg);
  }

  for (int i = tid; i < 2048; i += 128) ((unsigned int*)hbB)[i] = 0u;

  const unsigned short* sqb = seqb + ((size_t)(r0 + l15) * Ln) * Vn + lg * 8;
  bf16x8 sreg[4][2];

#define SEQ_PF(BI, T)                                                \
  { const int tp = ((T) < Ln) ? (T) : (Ln - 1);                      \
    const bf16x8* sp = (const bf16x8*)(sqb + (size_t)tp * Vn);       \
    sreg[BI][0] = sp[0];                                             \
    sreg[BI][1] = sp[4]; }

  SEQ_PF(0, 0)
  SEQ_PF(1, 1)
  SEQ_PF(2, 2)
  __syncthreads();

#define PHASE(P)                                                               \
  {                                                                            \
    const int cb = (P) & 1;                                                    \
    const unsigned char* zb = hbB[cb] + l15 * 256;                             \
    const bf16x8 z0 = *(const bf16x8*)(zb + ((16 * lg) ^ swz));                \
    const bf16x8 z1 = *(const bf16x8*)(zb + ((64 + 16 * lg) ^ swz));           \
    const bf16x8 z2 = *(const bf16x8*)(zb + ((128 + 16 * lg) ^ swz));          \
    const bf16x8 z3 = *(const bf16x8*)(zb + ((192 + 16 * lg) ^ swz));          \
    SEQ_PF(((P) + 3) & 3, t + (P) + 3);                                        \
    const bf16x8 s0 = sreg[(P)][0], s1 = sreg[(P)][1];                         \
    f32x4 p0 = bcv[0], p1 = bcv[1], p2 = bcv[2], p3 = bcv[3];                  \
    f32x4 q0 = {0.f, 0.f, 0.f, 0.f}, q1 = {0.f, 0.f, 0.f, 0.f};                \
    f32x4 q2 = {0.f, 0.f, 0.f, 0.f}, q3 = {0.f, 0.f, 0.f, 0.f};                \
    p0 = MFMA(Aw[0][0], s0, p0, 0, 0, 0);                                      \
    p1 = MFMA(Aw[1][0], s0, p1, 0, 0, 0);                                      \
    p2 = MFMA(Aw[2][0], s0, p2, 0, 0, 0);                                      \
    p3 = MFMA(Aw[3][0], s0, p3, 0, 0, 0);                                      \
    q0 = MFMA(Aw[0][1], s1, q0, 0, 0, 0);                                      \
    q1 = MFMA(Aw[1][1], s1, q1, 0, 0, 0);                                      \
    q2 = MFMA(Aw[2][1], s1, q2, 0, 0, 0);                                      \
    q3 = MFMA(Aw[3][1], s1, q3, 0, 0, 0);                                      \
    p0 = MFMA(Aw[0][2], z0, p0, 0, 0, 0);                                      \
    p1 = MFMA(Aw[1][2], z0, p1, 0, 0, 0);                                      \
    p2 = MFMA(Aw[2][2], z0, p2, 0, 0, 0);                                      \
    p3 = MFMA(Aw[3][2], z0, p3, 0, 0, 0);                                      \
    q0 = MFMA(Aw[0][3], z1, q0, 0, 0, 0);                                      \
    q1 = MFMA(Aw[1][3], z1, q1, 0, 0, 0);                                      \
    q2 = MFMA(Aw[2][3], z1, q2, 0, 0, 0);                                      \
    q3 = MFMA(Aw[3][3], z1, q3, 0, 0, 0);                                      \
    p0 = MFMA(Aw[0][4], z2, p0, 0, 0, 0);                                      \
    p1 = MFMA(Aw[1][4], z2, p1, 0, 0, 0);                                      \
    p2 = MFMA(Aw[2][4], z2, p2, 0, 0, 0);                                      \
    p3 = MFMA(Aw[3][4], z2, p3, 0, 0, 0);                                      \
    q0 = MFMA(Aw[0][5], z3, q0, 0, 0, 0);                                      \
    q1 = MFMA(Aw[1][5], z3, q1, 0, 0, 0);                                      \
    q2 = MFMA(Aw[2][5], z3, q2, 0, 0, 0);                                      \
    q3 = MFMA(Aw[3][5], z3, q3, 0, 0, 0);                                      \
    unsigned char* wbB = hbB[cb ^ 1] + l15 * 256;                              \
    _Pragma("unroll") for (int nn = 0; nn < 4; ++nn) {                         \
      const f32x4 pp = (nn == 0) ? p0 : (nn == 1) ? p1 : (nn == 2) ? p2 : p3;  \
      const f32x4 qq = (nn == 0) ? q0 : (nn == 1) ? q1 : (nn == 2) ? q2 : q3;  \
      const float r0v = fmaxf(pp[0] + qq[0], 0.f);                             \
      const float r1v = fmaxf(pp[1] + qq[1], 0.f);                             \
      const float r2v = fmaxf(pp[2] + qq[2], 0.f);                             \
      const float r3v = fmaxf(pp[3] + qq[3], 0.f);                             \
      unsigned d0, d1;                                                         \
      asm("v_cvt_pk_bf16_f32 %0, %1, %2" : "=v"(d0) : "v"(r0v), "v"(r1v));     \
      asm("v_cvt_pk_bf16_f32 %0, %1, %2" : "=v"(d1) : "v"(r2v), "v"(r3v));     \
      uint2 dd; dd.x = d0; dd.y = d1;                                          \
      *(uint2*)(wbB + ((128 * w + 32 * nn + 8 * lg) ^ swz)) = dd;              \
    }                                                                          \
    asm volatile("s_waitcnt lgkmcnt(0)" ::: "memory");                         \
    __builtin_amdgcn_s_barrier();                                              \
    asm volatile("" ::: "memory");                                             \
  }

#pragma unroll 1
  for (int t = 0; t < Ln; t += 4) {
    PHASE(0)
    PHASE(1)
    PHASE(2)
    PHASE(3)
  }
#undef PHASE
#undef SEQ_PF

  bf16x8 hz[4];
  const unsigned char* zb0 = hbB[0] + l15 * 256;
#pragma unroll
  for (int kt = 0; kt < 4; ++kt)
    hz[kt] = *(const bf16x8*)(zb0 + ((64 * kt + 16 * lg) ^ swz));
#pragma unroll
  for (int m = 0; m < 2; ++m) {
    const int v = 16 * (2 * w + m) + l15;
    const float* wor = W_out + (size_t)v * En + lg * 8;
    const float bo = b_out[v];
    f32x4 oa = {bo, bo, bo, bo};
#pragma unroll
    for (int kt = 0; kt < 4; ++kt) {
      float tmp[8];
      const float* p = wor + kt * 32;
#pragma unroll
      for (int i = 0; i < 8; ++i) tmp[i] = p[i];
      oa = MFMA(hz[kt], pack8(tmp), oa, 0, 0, 0);
    }
#pragma unroll
    for (int i = 0; i < 4; ++i)
      out[(size_t)(r0 + 4 * lg + i) * Vn + v] = oa[i];
  }
}

// ---------------- fp32 fallback (no workspace needed) ----------------

__global__ __launch_bounds__(256, 1) void rnn_mfma(
    const float* __restrict__ seq, const float* __restrict__ W_in,
    const float* __restrict__ b_in, const float* __restrict__ W_h,
    const float* __restrict__ b_h, const float* __restrict__ W_out,
    const float* __restrict__ b_out, float* __restrict__ out) {
  __shared__ __align__(16) unsigned short hb[2][16][HP];

  const int tid = threadIdx.x;
  const int w   = tid >> 6;
  const int l   = tid & 63;
  const int l15 = l & 15;
  const int lg  = l >> 4;
  const int r0  = blockIdx.x * 16;

  bf16x8 Bw[2][6];
  float bc[2];
#pragma unroll
  for (int n = 0; n < 2; ++n) {
    const int j = 32 * w + 16 * n + l15;
    const float* whr = W_h + j * (2 * En);
    float b = b_h[j];
    for (int e = 0; e < En; ++e) b = fmaf(b_in[e], whr[e], b);
    bc[n] = b;
#pragma unroll
    for (int kt = 0; kt < 6; ++kt) {
      float v[8];
#pragma unroll
      for (int i = 0; i < 8; ++i) {
        const int k = kt * 32 + lg * 8 + i;
        if (k < Vn) {
          float s = 0.f;
          for (int e = 0; e < En; ++e) s = fmaf(W_in[e * Vn + k], whr[e], s);
          v[i] = s;
        } else {
          v[i] = whr[Vn + k];
        }
      }
      Bw[n][kt] = pack8(v);
    }
  }

  for (int i = tid; i < 2 * 16 * HP; i += 256) ((unsigned short*)hb)[i] = 0;

  const float* sq = seq + ((size_t)(r0 + l15) * Ln) * Vn + lg * 8;
  f32x4 sbuf[4][4];

#define SEQ_PF(BI, T)                                                 \
  { const int tp = ((T) < Ln) ? (T) : (Ln - 1);                       \
    const f32x4* p0 = (const f32x4*)(sq + (size_t)tp * Vn);           \
    const f32x4* p1 = (const f32x4*)(sq + (size_t)tp * Vn + 32);      \
    sbuf[BI][0] = p0[0]; sbuf[BI][1] = p0[1];                         \
    sbuf[BI][2] = p1[0]; sbuf[BI][3] = p1[1]; }

  SEQ_PF(0, 0)
  SEQ_PF(1, 1)
  SEQ_PF(2, 2)
  __syncthreads();

#define PHASE(P)                                                              \
  {                                                                           \
    const int cb = (P) & 1, nb = cb ^ 1;                                      \
    const bf16x8 h0 = *(const bf16x8*)&hb[cb][l15][lg * 8];                   \
    const bf16x8 h1 = *(const bf16x8*)&hb[cb][l15][32 + lg * 8];              \
    const bf16x8 h2 = *(const bf16x8*)&hb[cb][l15][64 + lg * 8];              \
    const bf16x8 h3 = *(const bf16x8*)&hb[cb][l15][96 + lg * 8];              \
    SEQ_PF(((P) + 3) & 3, t + (P) + 3);                                       \
    float v0[8], v1[8];                                                       \
    _Pragma("unroll") for (int i = 0; i < 4; ++i) {                           \
      v0[i] = sbuf[(P)][0][i]; v0[4 + i] = sbuf[(P)][1][i];                   \
      v1[i] = sbuf[(P)][2][i]; v1[4 + i] = sbuf[(P)][3][i];                   \
    }                                                                         \
    const bf16x8 a0 = pack8(v0), a1 = pack8(v1);                              \
    f32x4 p0a = {bc[0], bc[0], bc[0], bc[0]};                                 \
    f32x4 p1a = {bc[1], bc[1], bc[1], bc[1]};                                 \
    f32x4 q0a = {0.f, 0.f, 0.f, 0.f}, q1a = {0.f, 0.f, 0.f, 0.f};             \
    p0a = MFMA(a0, Bw[0][0], p0a, 0, 0, 0);                                   \
    p1a = MFMA(a0, Bw[1][0], p1a, 0, 0, 0);                                   \
    p0a = MFMA(a1, Bw[0][1], p0a, 0, 0, 0);                                   \
    p1a = MFMA(a1, Bw[1][1], p1a, 0, 0, 0);                                   \
    p0a = MFMA(h0, Bw[0][2], p0a, 0, 0, 0);                                   \
    p1a = MFMA(h0, Bw[1][2], p1a, 0, 0, 0);                                   \
    q0a = MFMA(h2, Bw[0][4], q0a, 0, 0, 0);                                   \
    q1a = MFMA(h2, Bw[1][4], q1a, 0, 0, 0);                                   \
    p0a = MFMA(h1, Bw[0][3], p0a, 0, 0, 0);                                   \
    p1a = MFMA(h1, Bw[1][3], p1a, 0, 0, 0);                                   \
    q0a = MFMA(h3, Bw[0][5], q0a, 0, 0, 0);                                   \
    q1a = MFMA(h3, Bw[1][5], q1a, 0, 0, 0);                                   \
    const int j0 = 32 * w + l15, j1 = j0 + 16, rr = 4 * lg;                   \
    _Pragma("unroll") for (int i = 0; i < 4; ++i) {                           \
      hb[nb][rr + i][j0] = (unsigned short)f2b(fmaxf(p0a[i] + q0a[i], 0.f));  \
      hb[nb][rr + i][j1] = (unsigned short)f2b(fmaxf(p1a[i] + q1a[i], 0.f));  \
    }                                                                         \
    asm volatile("s_waitcnt lgkmcnt(0)" ::: "memory");                        \
    __builtin_amdgcn_s_barrier();                                             \
    asm volatile("" ::: "memory");                                            \
  }

#pragma unroll 1
  for (int t = 0; t < Ln; t += 4) {
    PHASE(0)
    PHASE(1)
    PHASE(2)
    PHASE(3)
  }
#undef PHASE
#undef SEQ_PF

  const int orow = tid >> 4;
  const int oc   = (tid & 15) * 4;
  float o0 = b_out[oc], o1 = b_out[oc + 1], o2 = b_out[oc + 2], o3 = b_out[oc + 3];
  const float* w0 = W_out + (size_t)(oc + 0) * En;
  const float* w1 = W_out + (size_t)(oc + 1) * En;
  const float* w2 = W_out + (size_t)(oc + 2) * En;
  const float* w3 = W_out + (size_t)(oc + 3) * En;
#pragma unroll 8
  for (int k = 0; k < En; ++k) {
    const float hv = b2f(hb[0][orow][k]);
    o0 = fmaf(hv, w0[k], o0);
    o1 = fmaf(hv, w1[k], o1);
    o2 = fmaf(hv, w2[k], o2);
    o3 = fmaf(hv, w3[k], o3);
  }
  *(float4*)&out[(size_t)(r0 + orow) * Vn + oc] = make_float4(o0, o1, o2, o3);
}

extern "C" void kernel_launch(void* const* d_in, const int* in_sizes, int n_in,
                              void* d_out, int out_size, void* d_ws, size_t ws_size,
                              hipStream_t stream) {
  const float* seq   = (const float*)d_in[0];
  const float* W_in  = (const float*)d_in[1];
  const float* b_in  = (const float*)d_in[2];
  const float* W_h   = (const float*)d_in[3];
  const float* b_h   = (const float*)d_in[4];
  const float* W_out = (const float*)d_in[5];
  const float* b_out = (const float*)d_in[6];
  float* out = (float*)d_out;

  if (ws_size >= FAST_WS2) {
    unsigned short* seqb  = (unsigned short*)d_ws;
    unsigned short* wall2 = (unsigned short*)((char*)d_ws + SEQB_BYTES);
    float* bc             = (float*)((char*)d_ws + SEQB_BYTES + WALLB_BYTES);
    unsigned short* woutp = (unsigned short*)((char*)d_ws + SEQB_BYTES + WALLB_BYTES + BC_BYTES);
    seq_cvt<<<2048, 256, 0, stream>>>(seq, seqb);
    rnn_setup2<<<En, Kc, 0, stream>>>(W_in, b_in, W_h, b_h, wall2, bc);
    wout_setup<<<Vn, En, 0, stream>>>(W_out, woutp);
    rnn_reg<<<Bn / 16, 64, 0, stream>>>(seqb, wall2, bc, woutp, b_out, out);
  } else if (ws_size >= FAST_WS) {
    unsigned short* seqb  = (unsigned short*)d_ws;
    unsigned short* wallb = (unsigned short*)((char*)d_ws + SEQB_BYTES);
    float* bc = (float*)((char*)d_ws + SEQB_BYTES + WALLB_BYTES);
    seq_cvt<<<2048, 256, 0, stream>>>(seq, seqb);
    rnn_setup_bf<<<En, Kc, 0, stream>>>(W_in, b_in, W_h, b_h, wallb, bc);
    rnn_fast2<<<Bn / 16, 128, 0, stream>>>(seqb, wallb, bc, W_out, b_out, out);
  } else {
    rnn_mfma<<<Bn / 16, 256, 0, stream>>>(seq, W_in, b_in, W_h, b_h, W_out, b_out, out);
  }
}

// Round 8
// 493.154 us; speedup vs baseline: 1.6308x; 1.6308x over previous
//
#include <hip/hip_runtime.h>
#include <hip/hip_bf16.h>

namespace {
constexpr int Bn = 512;
constexpr int Ln = 1024;
constexpr int Vn = 64;
constexpr int En = 128;
constexpr int Kc = Vn + En;              // 192
constexpr size_t SEQB_BYTES  = (size_t)Bn * Ln * Vn * 2;  // 67,108,864
constexpr size_t WALLB_BYTES = (size_t)En * Kc * 2;       // 49,152
constexpr size_t BC_BYTES    = En * 4;                    // 512
constexpr size_t WOUTP_BYTES = (size_t)Vn * En * 2;       // 16,384
constexpr size_t FAST_WS  = SEQB_BYTES + WALLB_BYTES + BC_BYTES;               // LDS path
constexpr size_t FAST_WS2 = SEQB_BYTES + WALLB_BYTES + BC_BYTES + WOUTP_BYTES; // reg path
}

typedef __attribute__((ext_vector_type(8))) short bf16x8;
typedef __attribute__((ext_vector_type(4))) float f32x4;
typedef __attribute__((ext_vector_type(8))) unsigned short u16x8;

__device__ __forceinline__ unsigned f2b(float f) {
  unsigned u = __float_as_uint(f);
  u += 0x7fffu + ((u >> 16) & 1u);
  return u >> 16;
}
__device__ __forceinline__ float b2f(unsigned short b) {
  return __uint_as_float(((unsigned)b) << 16);
}
__device__ __forceinline__ bf16x8 pack8(const float* v) {
  bf16x8 r;
#pragma unroll
  for (int i = 0; i < 8; ++i) r[i] = (short)f2b(v[i]);
  return r;
}

// column permutation for the in-register h cycle (4-wave split):
// produced: z k-tile w, elem (lg, e=4*hi+i)  <- h col 32w + 16*hi + 4*lg + i
// consumed: B-frag k index kk = 32w + 8*lg + 4*hi + i
// -> m(kk) = 32*(kk>>5) + 16*((kk>>2)&1) + 4*((kk>>3)&3) + (kk&3)
__device__ __forceinline__ int cm4(int kk) {
  return 32 * (kk >> 5) + 16 * ((kk >> 2) & 1) + 4 * ((kk >> 3) & 3) + (kk & 3);
}

#define MFMA __builtin_amdgcn_mfma_f32_16x16x32_bf16

// ---------------- setup kernels ----------------

// seq fp32 -> bf16 (bulk, memory-bound)
__global__ void seq_cvt(const float* __restrict__ seq, unsigned short* __restrict__ seqb) {
  const size_t n = (size_t)Bn * Ln * Vn;
  size_t i = ((size_t)blockIdx.x * blockDim.x + threadIdx.x) * 8;
  const size_t stride = (size_t)gridDim.x * blockDim.x * 8;
  for (; i < n; i += stride) {
    const f32x4 a = *(const f32x4*)(seq + i);
    const f32x4 b = *(const f32x4*)(seq + i + 4);
    u16x8 o;
#pragma unroll
    for (int j = 0; j < 4; ++j) o[j] = (unsigned short)f2b(a[j]);
#pragma unroll
    for (int j = 0; j < 4; ++j) o[4 + j] = (unsigned short)f2b(b[j]);
    *(u16x8*)(seqb + i) = o;
  }
}

// Wall2[j][k] bf16: k<64 -> folded input proj; k>=64 -> Whh[j][cm4(k-64)]
// bc[j] f32 = b_h[j] + sum_e b_in[e]*W_h[j][e]
__global__ void rnn_setup2(const float* __restrict__ W_in, const float* __restrict__ b_in,
                           const float* __restrict__ W_h, const float* __restrict__ b_h,
                           unsigned short* __restrict__ wall2, float* __restrict__ bc) {
  const int j = blockIdx.x;    // 0..127
  const int k = threadIdx.x;   // 0..191
  const float* whr = W_h + j * (2 * En);
  float s;
  if (k < Vn) {
    s = 0.f;
#pragma unroll 8
    for (int e = 0; e < En; ++e) s = fmaf(W_in[e * Vn + k], whr[e], s);
  } else {
    s = whr[En + cm4(k - Vn)];
  }
  wall2[j * Kc + k] = (unsigned short)f2b(s);
  if (k == 0) {
    float b = b_h[j];
    for (int e = 0; e < En; ++e) b = fmaf(b_in[e], whr[e], b);
    bc[j] = b;
  }
}

// woutp[v][kk] = W_out[v][cm4(kk)] (bf16)
__global__ void wout_setup(const float* __restrict__ W_out, unsigned short* __restrict__ woutp) {
  const int v = blockIdx.x;    // 0..63
  const int kk = threadIdx.x;  // 0..127
  woutp[v * En + kk] = (unsigned short)f2b(W_out[(size_t)v * En + cm4(kk)]);
}

// ---------------- main kernel: 2 groups x 4 waves, h in registers ----------------
// Group g handles batch rows blockIdx*32 + 16g .. +15. Wave w (0..3) of a group
// owns n-tiles {2w, 2w+1} (output cols 32w..32w+31) and produces z k-tile w,
// which stays in registers; the other 3 k-tiles are exchanged via LDS
// (1 ds_write_b128 + 3 ds_read_b128 per wave per step, conflict-free).
// 8 waves/block -> 2 waves/SIMD: saturates the MFMA pipe that a single wave cannot.
__global__ __launch_bounds__(512, 2) void rnn_grp(
    const unsigned short* __restrict__ seqb, const unsigned short* __restrict__ wall2,
    const float* __restrict__ bc, const unsigned short* __restrict__ woutp,
    const float* __restrict__ b_out, float* __restrict__ out) {
  __shared__ __align__(16) unsigned char zlds[2][2][4][1024];  // [group][buf][kt][lane16B]

  const int tid = threadIdx.x;
  const int wvi = tid >> 6;        // wave 0..7
  const int g   = wvi >> 2;        // group 0..1
  const int w   = wvi & 3;         // wave-in-group = owned z k-tile
  const int l   = tid & 63;
  const int l15 = l & 15;
  const int lg  = l >> 4;
  const int r0  = blockIdx.x * 32 + g * 16;

  // weights: Aw[nn][0,1] = seq k-tiles; Aw[nn][2+p] = z k-tile (w+p)&3 (own first)
  bf16x8 Aw[2][6];
#pragma unroll
  for (int nn = 0; nn < 2; ++nn) {
    const unsigned short* row = wall2 + (size_t)(32 * w + 16 * nn + l15) * Kc + lg * 8;
    Aw[nn][0] = *(const bf16x8*)(row);
    Aw[nn][1] = *(const bf16x8*)(row + 32);
#pragma unroll
    for (int p = 0; p < 4; ++p)
      Aw[nn][2 + p] = *(const bf16x8*)(row + Vn + 32 * ((w + p) & 3));
  }
  f32x4 bcv0 = *(const f32x4*)(bc + 32 * w + 4 * lg);
  f32x4 bcv1 = *(const f32x4*)(bc + 32 * w + 16 + 4 * lg);

  // LDS addresses (computed once)
  const int lane_off = (l15 * 4 + lg) * 16;
  unsigned char* wr0 = &zlds[g][0][w][lane_off];  // write z(t+1) when (t+1)&1==0
  unsigned char* wr1 = &zlds[g][1][w][lane_off];
  const unsigned char* rA0 = &zlds[g][0][(w + 1) & 3][lane_off];  // reads from buf0
  const unsigned char* rA1 = &zlds[g][0][(w + 2) & 3][lane_off];
  const unsigned char* rA2 = &zlds[g][0][(w + 3) & 3][lane_off];
  const unsigned char* rB0 = &zlds[g][1][(w + 1) & 3][lane_off];  // reads from buf1
  const unsigned char* rB1 = &zlds[g][1][(w + 2) & 3][lane_off];
  const unsigned char* rB2 = &zlds[g][1][(w + 3) & 3][lane_off];

  // h(0) = 0: zero all of zlds + own frag
  for (int i = tid; i < 4096; i += 512) ((unsigned int*)zlds)[i] = 0u;
  bf16x8 zown;
#pragma unroll
  for (int i = 0; i < 8; ++i) zown[i] = 0;

  // seq source: batch row r0+l15, elems lg*8.. (s0) and 32+lg*8.. (s1)
  const unsigned short* sqb = seqb + ((size_t)(r0 + l15) * Ln) * Vn + lg * 8;
  bf16x8 sreg[4][2];

#define SEQ_PF(BI, T)                                                \
  { const int tp = ((T) < Ln) ? (T) : (Ln - 1);                      \
    const bf16x8* sp = (const bf16x8*)(sqb + (size_t)tp * Vn);       \
    sreg[BI][0] = sp[0];                                             \
    sreg[BI][1] = sp[4]; }

  SEQ_PF(0, 0)
  SEQ_PF(1, 1)
  SEQ_PF(2, 2)
  __syncthreads();

#define PACK_Z(DST, PA, PB)                                                    \
  {                                                                            \
    const float x0 = fmaxf((PA)[0], 0.f), x1 = fmaxf((PA)[1], 0.f);            \
    const float x2 = fmaxf((PA)[2], 0.f), x3 = fmaxf((PA)[3], 0.f);            \
    const float y0 = fmaxf((PB)[0], 0.f), y1 = fmaxf((PB)[1], 0.f);            \
    const float y2 = fmaxf((PB)[2], 0.f), y3 = fmaxf((PB)[3], 0.f);            \
    unsigned u0, u1, u2, u3;                                                   \
    asm("v_cvt_pk_bf16_f32 %0, %1, %2" : "=v"(u0) : "v"(x0), "v"(x1));         \
    asm("v_cvt_pk_bf16_f32 %0, %1, %2" : "=v"(u1) : "v"(x2), "v"(x3));         \
    asm("v_cvt_pk_bf16_f32 %0, %1, %2" : "=v"(u2) : "v"(y0), "v"(y1));         \
    asm("v_cvt_pk_bf16_f32 %0, %1, %2" : "=v"(u3) : "v"(y2), "v"(y3));         \
    union { unsigned u[4]; bf16x8 v; } c_;                                     \
    c_.u[0] = u0; c_.u[1] = u1; c_.u[2] = u2; c_.u[3] = u3;                    \
    DST = c_.v;                                                                \
  }

  // step t (phase P): read foreign z(t) from buf[t&1], own z(t) = zown;
  // compute h(t+1); zown <- packed own tile; write own tile to buf[(t+1)&1].
#define PHASE(P, R0, R1, R2, WR)                                               \
  {                                                                            \
    const bf16x8 f0 = *(const bf16x8*)(R0);                                    \
    const bf16x8 f1 = *(const bf16x8*)(R1);                                    \
    const bf16x8 f2 = *(const bf16x8*)(R2);                                    \
    SEQ_PF(((P) + 3) & 3, t + (P) + 3);                                        \
    const bf16x8 s0 = sreg[(P)][0], s1 = sreg[(P)][1];                         \
    f32x4 p0 = bcv0, p1 = bcv1;                                                \
    f32x4 q0 = {0.f, 0.f, 0.f, 0.f}, q1 = {0.f, 0.f, 0.f, 0.f};                \
    p0 = MFMA(Aw[0][0], s0, p0, 0, 0, 0);                                      \
    p1 = MFMA(Aw[1][0], s0, p1, 0, 0, 0);                                      \
    q0 = MFMA(Aw[0][1], s1, q0, 0, 0, 0);                                      \
    q1 = MFMA(Aw[1][1], s1, q1, 0, 0, 0);                                      \
    p0 = MFMA(Aw[0][2], zown, p0, 0, 0, 0);                                    \
    p1 = MFMA(Aw[1][2], zown, p1, 0, 0, 0);                                    \
    q0 = MFMA(Aw[0][3], f0, q0, 0, 0, 0);                                      \
    q1 = MFMA(Aw[1][3], f0, q1, 0, 0, 0);                                      \
    p0 = MFMA(Aw[0][4], f1, p0, 0, 0, 0);                                      \
    p1 = MFMA(Aw[1][4], f1, p1, 0, 0, 0);                                      \
    q0 = MFMA(Aw[0][5], f2, q0, 0, 0, 0);                                      \
    q1 = MFMA(Aw[1][5], f2, q1, 0, 0, 0);                                      \
    const f32x4 a0 = p0 + q0, a1 = p1 + q1;                                    \
    PACK_Z(zown, a0, a1);                                                      \
    *(bf16x8*)(WR) = zown;                                                     \
    asm volatile("s_waitcnt lgkmcnt(0)" ::: "memory");                         \
    __builtin_amdgcn_s_barrier();                                              \
    asm volatile("" ::: "memory");                                             \
  }

#pragma unroll 1
  for (int t = 0; t < Ln; t += 4) {
    PHASE(0, rA0, rA1, rA2, wr1)  // t%4==0: read buf0, write buf1
    PHASE(1, rB0, rB1, rB2, wr0)
    PHASE(2, rA0, rA1, rA2, wr1)
    PHASE(3, rB0, rB1, rB2, wr0)
  }
#undef PHASE
#undef SEQ_PF

  // epilogue: h(1024) own tile in zown, foreign in buf0. Wave w -> v-tile w.
  {
    const bf16x8 f0 = *(const bf16x8*)(rA0);
    const bf16x8 f1 = *(const bf16x8*)(rA1);
    const bf16x8 f2 = *(const bf16x8*)(rA2);
    f32x4 o = *(const f32x4*)(b_out + 16 * w + 4 * lg);
    const unsigned short* wrow = woutp + (size_t)(16 * w + l15) * En + lg * 8;
    const bf16x8 wv0 = *(const bf16x8*)(wrow + 32 * ((w + 0) & 3));
    const bf16x8 wv1 = *(const bf16x8*)(wrow + 32 * ((w + 1) & 3));
    const bf16x8 wv2 = *(const bf16x8*)(wrow + 32 * ((w + 2) & 3));
    const bf16x8 wv3 = *(const bf16x8*)(wrow + 32 * ((w + 3) & 3));
    o = MFMA(wv0, zown, o, 0, 0, 0);
    o = MFMA(wv1, f0, o, 0, 0, 0);
    o = MFMA(wv2, f1, o, 0, 0, 0);
    o = MFMA(wv3, f2, o, 0, 0, 0);
    *(f32x4*)&out[(size_t)(r0 + l15) * Vn + 16 * w + 4 * lg] = o;
  }
}

// ---------------- round-6 LDS fast path (fallback #1) ----------------

__global__ void rnn_setup_bf(const float* __restrict__ W_in, const float* __restrict__ b_in,
                             const float* __restrict__ W_h, const float* __restrict__ b_h,
                             unsigned short* __restrict__ wallb, float* __restrict__ bc) {
  const int j = blockIdx.x;
  const int k = threadIdx.x;
  const float* whr = W_h + j * (2 * En);
  float s;
  if (k < Vn) {
    s = 0.f;
#pragma unroll 8
    for (int e = 0; e < En; ++e) s = fmaf(W_in[e * Vn + k], whr[e], s);
  } else {
    s = whr[Vn + k];
  }
  wallb[j * Kc + k] = (unsigned short)f2b(s);
  if (k == 0) {
    float b = b_h[j];
    for (int e = 0; e < En; ++e) b = fmaf(b_in[e], whr[e], b);
    bc[j] = b;
  }
}

__global__ __launch_bounds__(128, 1) void rnn_fast2(
    const unsigned short* __restrict__ seqb, const unsigned short* __restrict__ wallb,
    const float* __restrict__ bc, const float* __restrict__ W_out,
    const float* __restrict__ b_out, float* __restrict__ out) {
  __shared__ __align__(16) unsigned char hbB[2][4096];

  const int tid = threadIdx.x;
  const int w   = tid >> 6;
  const int l   = tid & 63;
  const int l15 = l & 15;
  const int lg  = l >> 4;
  const int r0  = blockIdx.x * 16;
  const int swz = (l15 & 7) << 4;

  bf16x8 Aw[4][6];
  f32x4 bcv[4];
#pragma unroll
  for (int nn = 0; nn < 4; ++nn) {
    const int n = 4 * w + nn;
    const unsigned short* p = wallb + (size_t)(16 * n + l15) * Kc + lg * 8;
#pragma unroll
    for (int kt = 0; kt < 6; ++kt) Aw[nn][kt] = *(const bf16x8*)(p + kt * 32);
    bcv[nn] = *(const f32x4*)(bc + 16 * n + 4 * lg);
  }

  for (int i = tid; i < 2048; i += 128) ((unsigned int*)hbB)[i] = 0u;

  const unsigned short* sqb = seqb + ((size_t)(r0 + l15) * Ln) * Vn + lg * 8;
  bf16x8 sreg[4][2];

#define SEQ_PF(BI, T)                                                \
  { const int tp = ((T) < Ln) ? (T) : (Ln - 1);                      \
    const bf16x8* sp = (const bf16x8*)(sqb + (size_t)tp * Vn);       \
    sreg[BI][0] = sp[0];                                             \
    sreg[BI][1] = sp[4]; }

  SEQ_PF(0, 0)
  SEQ_PF(1, 1)
  SEQ_PF(2, 2)
  __syncthreads();

#define PHASE(P)                                                               \
  {                                                                            \
    const int cb = (P) & 1;                                                    \
    const unsigned char* zb = hbB[cb] + l15 * 256;                             \
    const bf16x8 z0 = *(const bf16x8*)(zb + ((16 * lg) ^ swz));                \
    const bf16x8 z1 = *(const bf16x8*)(zb + ((64 + 16 * lg) ^ swz));           \
    const bf16x8 z2 = *(const bf16x8*)(zb + ((128 + 16 * lg) ^ swz));          \
    const bf16x8 z3 = *(const bf16x8*)(zb + ((192 + 16 * lg) ^ swz));          \
    SEQ_PF(((P) + 3) & 3, t + (P) + 3);                                        \
    const bf16x8 s0 = sreg[(P)][0], s1 = sreg[(P)][1];                         \
    f32x4 p0 = bcv[0], p1 = bcv[1], p2 = bcv[2], p3 = bcv[3];                  \
    f32x4 q0 = {0.f, 0.f, 0.f, 0.f}, q1 = {0.f, 0.f, 0.f, 0.f};                \
    f32x4 q2 = {0.f, 0.f, 0.f, 0.f}, q3 = {0.f, 0.f, 0.f, 0.f};                \
    p0 = MFMA(Aw[0][0], s0, p0, 0, 0, 0);                                      \
    p1 = MFMA(Aw[1][0], s0, p1, 0, 0, 0);                                      \
    p2 = MFMA(Aw[2][0], s0, p2, 0, 0, 0);                                      \
    p3 = MFMA(Aw[3][0], s0, p3, 0, 0, 0);                                      \
    q0 = MFMA(Aw[0][1], s1, q0, 0, 0, 0);                                      \
    q1 = MFMA(Aw[1][1], s1, q1, 0, 0, 0);                                      \
    q2 = MFMA(Aw[2][1], s1, q2, 0, 0, 0);                                      \
    q3 = MFMA(Aw[3][1], s1, q3, 0, 0, 0);                                      \
    p0 = MFMA(Aw[0][2], z0, p0, 0, 0, 0);                                      \
    p1 = MFMA(Aw[1][2], z0, p1, 0, 0, 0);                                      \
    p2 = MFMA(Aw[2][2], z0, p2, 0, 0, 0);                                      \
    p3 = MFMA(Aw[3][2], z0, p3, 0, 0, 0);                                      \
    q0 = MFMA(Aw[0][3], z1, q0, 0, 0, 0);                                      \
    q1 = MFMA(Aw[1][3], z1, q1, 0, 0, 0);                                      \
    q2 = MFMA(Aw[2][3], z1, q2, 0, 0, 0);                                      \
    q3 = MFMA(Aw[3][3], z1, q3, 0, 0, 0);                                      \
    p0 = MFMA(Aw[0][4], z2, p0, 0, 0, 0);                                      \
    p1 = MFMA(Aw[1][4], z2, p1, 0, 0, 0);                                      \
    p2 = MFMA(Aw[2][4], z2, p2, 0, 0, 0);                                      \
    p3 = MFMA(Aw[3][4], z2, p3, 0, 0, 0);                                      \
    q0 = MFMA(Aw[0][5], z3, q0, 0, 0, 0);                                      \
    q1 = MFMA(Aw[1][5], z3, q1, 0, 0, 0);                                      \
    q2 = MFMA(Aw[2][5], z3, q2, 0, 0, 0);                                      \
    q3 = MFMA(Aw[3][5], z3, q3, 0, 0, 0);                                      \
    unsigned char* wbB = hbB[cb ^ 1] + l15 * 256;                              \
    _Pragma("unroll") for (int nn = 0; nn < 4; ++nn) {                         \
      const f32x4 pp = (nn == 0) ? p0 : (nn == 1) ? p1 : (nn == 2) ? p2 : p3;  \
      const f32x4 qq = (nn == 0) ? q0 : (nn == 1) ? q1 : (nn == 2) ? q2 : q3;  \
      const float r0v = fmaxf(pp[0] + qq[0], 0.f);                             \
      const float r1v = fmaxf(pp[1] + qq[1], 0.f);                             \
      const float r2v = fmaxf(pp[2] + qq[2], 0.f);                             \
      const float r3v = fmaxf(pp[3] + qq[3], 0.f);                             \
      unsigned d0, d1;                                                         \
      asm("v_cvt_pk_bf16_f32 %0, %1, %2" : "=v"(d0) : "v"(r0v), "v"(r1v));     \
      asm("v_cvt_pk_bf16_f32 %0, %1, %2" : "=v"(d1) : "v"(r2v), "v"(r3v));     \
      uint2 dd; dd.x = d0; dd.y = d1;                                          \
      *(uint2*)(wbB + ((128 * w + 32 * nn + 8 * lg) ^ swz)) = dd;              \
    }                                                                          \
    asm volatile("s_waitcnt lgkmcnt(0)" ::: "memory");                         \
    __builtin_amdgcn_s_barrier();                                              \
    asm volatile("" ::: "memory");                                             \
  }

#pragma unroll 1
  for (int t = 0; t < Ln; t += 4) {
    PHASE(0)
    PHASE(1)
    PHASE(2)
    PHASE(3)
  }
#undef PHASE
#undef SEQ_PF

  bf16x8 hz[4];
  const unsigned char* zb0 = hbB[0] + l15 * 256;
#pragma unroll
  for (int kt = 0; kt < 4; ++kt)
    hz[kt] = *(const bf16x8*)(zb0 + ((64 * kt + 16 * lg) ^ swz));
#pragma unroll
  for (int m = 0; m < 2; ++m) {
    const int v = 16 * (2 * w + m) + l15;
    const float* wor = W_out + (size_t)v * En + lg * 8;
    const float bo = b_out[v];
    f32x4 oa = {bo, bo, bo, bo};
#pragma unroll
    for (int kt = 0; kt < 4; ++kt) {
      float tmp[8];
      const float* p = wor + kt * 32;
#pragma unroll
      for (int i = 0; i < 8; ++i) tmp[i] = p[i];
      oa = MFMA(hz[kt], pack8(tmp), oa, 0, 0, 0);
    }
#pragma unroll
    for (int i = 0; i < 4; ++i)
      out[(size_t)(r0 + 4 * lg + i) * Vn + v] = oa[i];
  }
}

// ---------------- fp32 fallback (no workspace needed) ----------------

__global__ __launch_bounds__(256, 1) void rnn_mfma(
    const float* __restrict__ seq, const float* __restrict__ W_in,
    const float* __restrict__ b_in, const float* __restrict__ W_h,
    const float* __restrict__ b_h, const float* __restrict__ W_out,
    const float* __restrict__ b_out, float* __restrict__ out) {
  __shared__ __align__(16) unsigned short hb[2][16][136];

  const int tid = threadIdx.x;
  const int w   = tid >> 6;
  const int l   = tid & 63;
  const int l15 = l & 15;
  const int lg  = l >> 4;
  const int r0  = blockIdx.x * 16;

  bf16x8 Bw[2][6];
  float bc[2];
#pragma unroll
  for (int n = 0; n < 2; ++n) {
    const int j = 32 * w + 16 * n + l15;
    const float* whr = W_h + j * (2 * En);
    float b = b_h[j];
    for (int e = 0; e < En; ++e) b = fmaf(b_in[e], whr[e], b);
    bc[n] = b;
#pragma unroll
    for (int kt = 0; kt < 6; ++kt) {
      float v[8];
#pragma unroll
      for (int i = 0; i < 8; ++i) {
        const int k = kt * 32 + lg * 8 + i;
        if (k < Vn) {
          float s = 0.f;
          for (int e = 0; e < En; ++e) s = fmaf(W_in[e * Vn + k], whr[e], s);
          v[i] = s;
        } else {
          v[i] = whr[Vn + k];
        }
      }
      Bw[n][kt] = pack8(v);
    }
  }

  for (int i = tid; i < 2 * 16 * 136; i += 256) ((unsigned short*)hb)[i] = 0;

  const float* sq = seq + ((size_t)(r0 + l15) * Ln) * Vn + lg * 8;
  f32x4 sbuf[4][4];

#define SEQ_PF(BI, T)                                                 \
  { const int tp = ((T) < Ln) ? (T) : (Ln - 1);                       \
    const f32x4* p0 = (const f32x4*)(sq + (size_t)tp * Vn);           \
    const f32x4* p1 = (const f32x4*)(sq + (size_t)tp * Vn + 32);      \
    sbuf[BI][0] = p0[0]; sbuf[BI][1] = p0[1];                         \
    sbuf[BI][2] = p1[0]; sbuf[BI][3] = p1[1]; }

  SEQ_PF(0, 0)
  SEQ_PF(1, 1)
  SEQ_PF(2, 2)
  __syncthreads();

#define PHASE(P)                                                              \
  {                                                                           \
    const int cb = (P) & 1, nb = cb ^ 1;                                      \
    const bf16x8 h0 = *(const bf16x8*)&hb[cb][l15][lg * 8];                   \
    const bf16x8 h1 = *(const bf16x8*)&hb[cb][l15][32 + lg * 8];              \
    const bf16x8 h2 = *(const bf16x8*)&hb[cb][l15][64 + lg * 8];              \
    const bf16x8 h3 = *(const bf16x8*)&hb[cb][l15][96 + lg * 8];              \
    SEQ_PF(((P) + 3) & 3, t + (P) + 3);                                       \
    float v0[8], v1[8];                                                       \
    _Pragma("unroll") for (int i = 0; i < 4; ++i) {                           \
      v0[i] = sbuf[(P)][0][i]; v0[4 + i] = sbuf[(P)][1][i];                   \
      v1[i] = sbuf[(P)][2][i]; v1[4 + i] = sbuf[(P)][3][i];                   \
    }                                                                         \
    const bf16x8 a0 = pack8(v0), a1 = pack8(v1);                              \
    f32x4 p0a = {bc[0], bc[0], bc[0], bc[0]};                                 \
    f32x4 p1a = {bc[1], bc[1], bc[1], bc[1]};                                 \
    f32x4 q0a = {0.f, 0.f, 0.f, 0.f}, q1a = {0.f, 0.f, 0.f, 0.f};             \
    p0a = MFMA(a0, Bw[0][0], p0a, 0, 0, 0);                                   \
    p1a = MFMA(a0, Bw[1][0], p1a, 0, 0, 0);                                   \
    p0a = MFMA(a1, Bw[0][1], p0a, 0, 0, 0);                                   \
    p1a = MFMA(a1, Bw[1][1], p1a, 0, 0, 0);                                   \
    p0a = MFMA(h0, Bw[0][2], p0a, 0, 0, 0);                                   \
    p1a = MFMA(h0, Bw[1][2], p1a, 0, 0, 0);                                   \
    q0a = MFMA(h2, Bw[0][4], q0a, 0, 0, 0);                                   \
    q1a = MFMA(h2, Bw[1][4], q1a, 0, 0, 0);                                   \
    p0a = MFMA(h1, Bw[0][3], p0a, 0, 0, 0);                                   \
    p1a = MFMA(h1, Bw[1][3], p1a, 0, 0, 0);                                   \
    q0a = MFMA(h3, Bw[0][5], q0a, 0, 0, 0);                                   \
    q1a = MFMA(h3, Bw[1][5], q1a, 0, 0, 0);                                   \
    const int j0 = 32 * w + l15, j1 = j0 + 16, rr = 4 * lg;                   \
    _Pragma("unroll") for (int i = 0; i < 4; ++i) {                           \
      hb[nb][rr + i][j0] = (unsigned short)f2b(fmaxf(p0a[i] + q0a[i], 0.f));  \
      hb[nb][rr + i][j1] = (unsigned short)f2b(fmaxf(p1a[i] + q1a[i], 0.f));  \
    }                                                                         \
    asm volatile("s_waitcnt lgkmcnt(0)" ::: "memory");                        \
    __builtin_amdgcn_s_barrier();                                             \
    asm volatile("" ::: "memory");                                            \
  }

#pragma unroll 1
  for (int t = 0; t < Ln; t += 4) {
    PHASE(0)
    PHASE(1)
    PHASE(2)
    PHASE(3)
  }
#undef PHASE
#undef SEQ_PF

  const int orow = tid >> 4;
  const int oc   = (tid & 15) * 4;
  float o0 = b_out[oc], o1 = b_out[oc + 1], o2 = b_out[oc + 2], o3 = b_out[oc + 3];
  const float* w0 = W_out + (size_t)(oc + 0) * En;
  const float* w1 = W_out + (size_t)(oc + 1) * En;
  const float* w2 = W_out + (size_t)(oc + 2) * En;
  const float* w3 = W_out + (size_t)(oc + 3) * En;
#pragma unroll 8
  for (int k = 0; k < En; ++k) {
    const float hv = b2f(hb[0][orow][k]);
    o0 = fmaf(hv, w0[k], o0);
    o1 = fmaf(hv, w1[k], o1);
    o2 = fmaf(hv, w2[k], o2);
    o3 = fmaf(hv, w3[k], o3);
  }
  *(float4*)&out[(size_t)(r0 + orow) * Vn + oc] = make_float4(o0, o1, o2, o3);
}

extern "C" void kernel_launch(void* const* d_in, const int* in_sizes, int n_in,
                              void* d_out, int out_size, void* d_ws, size_t ws_size,
                              hipStream_t stream) {
  const float* seq   = (const float*)d_in[0];
  const float* W_in  = (const float*)d_in[1];
  const float* b_in  = (const float*)d_in[2];
  const float* W_h   = (const float*)d_in[3];
  const float* b_h   = (const float*)d_in[4];
  const float* W_out = (const float*)d_in[5];
  const float* b_out = (const float*)d_in[6];
  float* out = (float*)d_out;

  if (ws_size >= FAST_WS2) {
    unsigned short* seqb  = (unsigned short*)d_ws;
    unsigned short* wall2 = (unsigned short*)((char*)d_ws + SEQB_BYTES);
    float* bc             = (float*)((char*)d_ws + SEQB_BYTES + WALLB_BYTES);
    unsigned short* woutp = (unsigned short*)((char*)d_ws + SEQB_BYTES + WALLB_BYTES + BC_BYTES);
    seq_cvt<<<2048, 256, 0, stream>>>(seq, seqb);
    rnn_setup2<<<En, Kc, 0, stream>>>(W_in, b_in, W_h, b_h, wall2, bc);
    wout_setup<<<Vn, En, 0, stream>>>(W_out, woutp);
    rnn_grp<<<Bn / 32, 512, 0, stream>>>(seqb, wall2, bc, woutp, b_out, out);
  } else if (ws_size >= FAST_WS) {
    unsigned short* seqb  = (unsigned short*)d_ws;
    unsigned short* wallb = (unsigned short*)((char*)d_ws + SEQB_BYTES);
    float* bc = (float*)((char*)d_ws + SEQB_BYTES + WALLB_BYTES);
    seq_cvt<<<2048, 256, 0, stream>>>(seq, seqb);
    rnn_setup_bf<<<En, Kc, 0, stream>>>(W_in, b_in, W_h, b_h, wallb, bc);
    rnn_fast2<<<Bn / 16, 128, 0, stream>>>(seqb, wallb, bc, W_out, b_out, out);
  } else {
    rnn_mfma<<<Bn / 16, 256, 0, stream>>>(seq, W_in, b_in, W_h, b_h, W_out, b_out, out);
  }
}

// Round 9
// 490.097 us; speedup vs baseline: 1.6410x; 1.0062x over previous
//
#include <hip/hip_runtime.h>
#include <hip/hip_bf16.h>

namespace {
constexpr int Bn = 512;
constexpr int Ln = 1024;
constexpr int Vn = 64;
constexpr int En = 128;
constexpr int Kc = Vn + En;              // 192
constexpr size_t SEQB_BYTES  = (size_t)Bn * Ln * Vn * 2;  // 67,108,864
constexpr size_t WALLB_BYTES = (size_t)En * Kc * 2;       // 49,152
constexpr size_t BC_BYTES    = En * 4;                    // 512
constexpr size_t WOUTP_BYTES = (size_t)Vn * En * 2;       // 16,384
constexpr size_t FAST_WS  = SEQB_BYTES + WALLB_BYTES + BC_BYTES;               // LDS path
constexpr size_t FAST_WS2 = SEQB_BYTES + WALLB_BYTES + BC_BYTES + WOUTP_BYTES; // reg path
constexpr int TS = 1056;                 // z-tile stride in LDS bytes (1024 + 32: 8-bank stagger)
}

typedef __attribute__((ext_vector_type(8))) short bf16x8;
typedef __attribute__((ext_vector_type(4))) float f32x4;
typedef __attribute__((ext_vector_type(8))) unsigned short u16x8;

__device__ __forceinline__ unsigned f2b(float f) {
  unsigned u = __float_as_uint(f);
  u += 0x7fffu + ((u >> 16) & 1u);
  return u >> 16;
}
__device__ __forceinline__ float b2f(unsigned short b) {
  return __uint_as_float(((unsigned)b) << 16);
}
__device__ __forceinline__ bf16x8 pack8(const float* v) {
  bf16x8 r;
#pragma unroll
  for (int i = 0; i < 8; ++i) r[i] = (short)f2b(v[i]);
  return r;
}

// column permutation for the in-register h cycle:
// z k-tile tau, elem e=4*hi+i at k-group lg  <->  h col 16*(2*tau+hi) + 4*lg + i
// -> m(kk) = 32*(kk>>5) + 16*((kk>>2)&1) + 4*((kk>>3)&3) + (kk&3)
__device__ __forceinline__ int cm4(int kk) {
  return 32 * (kk >> 5) + 16 * ((kk >> 2) & 1) + 4 * ((kk >> 3) & 3) + (kk & 3);
}

#define MFMA __builtin_amdgcn_mfma_f32_16x16x32_bf16

// ---------------- setup kernels ----------------

__global__ void seq_cvt(const float* __restrict__ seq, unsigned short* __restrict__ seqb) {
  const size_t n = (size_t)Bn * Ln * Vn;
  size_t i = ((size_t)blockIdx.x * blockDim.x + threadIdx.x) * 8;
  const size_t stride = (size_t)gridDim.x * blockDim.x * 8;
  for (; i < n; i += stride) {
    const f32x4 a = *(const f32x4*)(seq + i);
    const f32x4 b = *(const f32x4*)(seq + i + 4);
    u16x8 o;
#pragma unroll
    for (int j = 0; j < 4; ++j) o[j] = (unsigned short)f2b(a[j]);
#pragma unroll
    for (int j = 0; j < 4; ++j) o[4 + j] = (unsigned short)f2b(b[j]);
    *(u16x8*)(seqb + i) = o;
  }
}

// Wall2[j][k] bf16: k<64 -> folded input proj; k>=64 -> Whh[j][cm4(k-64)]
__global__ void rnn_setup2(const float* __restrict__ W_in, const float* __restrict__ b_in,
                           const float* __restrict__ W_h, const float* __restrict__ b_h,
                           unsigned short* __restrict__ wall2, float* __restrict__ bc) {
  const int j = blockIdx.x;    // 0..127
  const int k = threadIdx.x;   // 0..191
  const float* whr = W_h + j * (2 * En);
  float s;
  if (k < Vn) {
    s = 0.f;
#pragma unroll 8
    for (int e = 0; e < En; ++e) s = fmaf(W_in[e * Vn + k], whr[e], s);
  } else {
    s = whr[En + cm4(k - Vn)];
  }
  wall2[j * Kc + k] = (unsigned short)f2b(s);
  if (k == 0) {
    float b = b_h[j];
    for (int e = 0; e < En; ++e) b = fmaf(b_in[e], whr[e], b);
    bc[j] = b;
  }
}

__global__ void wout_setup(const float* __restrict__ W_out, unsigned short* __restrict__ woutp) {
  const int v = blockIdx.x;    // 0..63
  const int kk = threadIdx.x;  // 0..127
  woutp[v * En + kk] = (unsigned short)f2b(W_out[(size_t)v * En + cm4(kk)]);
}

// ---------------- main kernel: 8 waves, 6 MFMAs/wave, h mostly in registers ----
// Block = one group of 16 batch rows, 8 waves. Wave w owns h cols [16w,16w+16)
// = half (hi=w&1) of z k-tile tau=w>>1. Its packed relu output (uint2) is
// directly elems 4*hi..4*hi+3 of next step's B-frag (cm4 permutation).
// Exchange per step: write 8B, read sibling 8B + 3 foreign 16B from a
// bank-staggered (stride 1056B) double-buffered LDS region.
__global__ __launch_bounds__(512, 1) void rnn_grp8(
    const unsigned short* __restrict__ seqb, const unsigned short* __restrict__ wall2,
    const float* __restrict__ bc, const unsigned short* __restrict__ woutp,
    const float* __restrict__ b_out, float* __restrict__ out) {
  __shared__ __align__(16) unsigned char zlds[2 * 4 * TS];  // 2 bufs x 4 tiles x 1056B

  const int tid = threadIdx.x;
  const int w   = tid >> 6;        // wave 0..7
  const int tau = w >> 1;          // owned k-tile
  const int hi  = w & 1;           // owned half (elem group) within tile
  const int l   = tid & 63;
  const int l15 = l & 15;          // batch col / A row
  const int lg  = l >> 4;          // k-group
  const int r0  = blockIdx.x * 16;

  // weights: Aw[0,1] = seq k-tiles; Aw[2+p] = z k-tile (tau+p)&3 (own first)
  bf16x8 Aw[6];
  {
    const unsigned short* row = wall2 + (size_t)(16 * w + l15) * Kc + lg * 8;
    Aw[0] = *(const bf16x8*)(row);
    Aw[1] = *(const bf16x8*)(row + 32);
#pragma unroll
    for (int p = 0; p < 4; ++p)
      Aw[2 + p] = *(const bf16x8*)(row + Vn + 32 * ((tau + p) & 3));
  }
  const f32x4 bcv = *(const f32x4*)(bc + 16 * w + 4 * lg);

  const int slot   = (l15 * 4 + lg) * 16;
  const int ro_sib = tau * TS + slot + 8 * (1 - hi);
  const int ro1    = ((tau + 1) & 3) * TS + slot;
  const int ro2    = ((tau + 2) & 3) * TS + slot;
  const int ro3    = ((tau + 3) & 3) * TS + slot;
  const int wo     = tau * TS + slot + 8 * hi;

  // h(0) = 0
  for (int i = tid; i < 2 * 4 * TS / 4; i += 512) ((unsigned int*)zlds)[i] = 0u;
  uint2 zown;
  zown.x = 0u;
  zown.y = 0u;

  const unsigned short* sqb = seqb + ((size_t)(r0 + l15) * Ln) * Vn + lg * 8;
  bf16x8 sreg[4][2];

#define SEQ_PF(BI, T)                                                \
  { const int tp = ((T) < Ln) ? (T) : (Ln - 1);                      \
    const bf16x8* sp = (const bf16x8*)(sqb + (size_t)tp * Vn);       \
    sreg[BI][0] = sp[0];                                             \
    sreg[BI][1] = sp[4]; }

  SEQ_PF(0, 0)
  SEQ_PF(1, 1)
  SEQ_PF(2, 2)
  __syncthreads();

#define PHASE(P)                                                              \
  {                                                                           \
    const int cb = (P) & 1, nb = cb ^ 1;                                      \
    const unsigned char* base = zlds + cb * (4 * TS);                         \
    const uint2  sib = *(const uint2*)(base + ro_sib);                        \
    const bf16x8 zf1 = *(const bf16x8*)(base + ro1);                          \
    const bf16x8 zf2 = *(const bf16x8*)(base + ro2);                          \
    const bf16x8 zf3 = *(const bf16x8*)(base + ro3);                          \
    SEQ_PF(((P) + 3) & 3, t + (P) + 3);                                       \
    const uint2 w01 = hi ? sib : zown;                                        \
    const uint2 w23 = hi ? zown : sib;                                        \
    union { unsigned u[4]; bf16x8 v; } zo;                                    \
    zo.u[0] = w01.x; zo.u[1] = w01.y; zo.u[2] = w23.x; zo.u[3] = w23.y;       \
    const bf16x8 s0 = sreg[(P)][0], s1 = sreg[(P)][1];                        \
    f32x4 p = MFMA(Aw[0], s0, bcv, 0, 0, 0);                                  \
    f32x4 q = {0.f, 0.f, 0.f, 0.f};                                           \
    q = MFMA(Aw[1], s1, q, 0, 0, 0);                                          \
    p = MFMA(Aw[2], zo.v, p, 0, 0, 0);                                        \
    q = MFMA(Aw[3], zf1, q, 0, 0, 0);                                         \
    p = MFMA(Aw[4], zf2, p, 0, 0, 0);                                         \
    q = MFMA(Aw[5], zf3, q, 0, 0, 0);                                         \
    const f32x4 a = p + q;                                                    \
    const float r0v = fmaxf(a[0], 0.f), r1v = fmaxf(a[1], 0.f);               \
    const float r2v = fmaxf(a[2], 0.f), r3v = fmaxf(a[3], 0.f);               \
    asm("v_cvt_pk_bf16_f32 %0, %1, %2" : "=v"(zown.x) : "v"(r0v), "v"(r1v));  \
    asm("v_cvt_pk_bf16_f32 %0, %1, %2" : "=v"(zown.y) : "v"(r2v), "v"(r3v));  \
    *(uint2*)(zlds + nb * (4 * TS) + wo) = zown;                              \
    asm volatile("s_waitcnt lgkmcnt(0)" ::: "memory");                        \
    __builtin_amdgcn_s_barrier();                                             \
    asm volatile("" ::: "memory");                                            \
  }

#pragma unroll 1
  for (int t = 0; t < Ln; t += 4) {
    PHASE(0)
    PHASE(1)
    PHASE(2)
    PHASE(3)
  }
#undef PHASE
#undef SEQ_PF

  // epilogue: h(1024) fully in zlds buf0 (final write targeted buf0).
  // Waves 0..3 compute vocab tiles 0..3: out = h @ W_out^T + b_out.
  if (w < 4) {
    f32x4 o = *(const f32x4*)(b_out + 16 * w + 4 * lg);
#pragma unroll
    for (int p = 0; p < 4; ++p) {
      const int tp = (w + p) & 3;
      const bf16x8 zt = *(const bf16x8*)(zlds + tp * TS + slot);
      const bf16x8 wf =
          *(const bf16x8*)(woutp + (size_t)(16 * w + l15) * En + 32 * tp + lg * 8);
      o = MFMA(wf, zt, o, 0, 0, 0);
    }
    *(f32x4*)&out[(size_t)(r0 + l15) * Vn + 16 * w + 4 * lg] = o;
  }
}

// ---------------- round-6 LDS fast path (fallback #1) ----------------

__global__ void rnn_setup_bf(const float* __restrict__ W_in, const float* __restrict__ b_in,
                             const float* __restrict__ W_h, const float* __restrict__ b_h,
                             unsigned short* __restrict__ wallb, float* __restrict__ bc) {
  const int j = blockIdx.x;
  const int k = threadIdx.x;
  const float* whr = W_h + j * (2 * En);
  float s;
  if (k < Vn) {
    s = 0.f;
#pragma unroll 8
    for (int e = 0; e < En; ++e) s = fmaf(W_in[e * Vn + k], whr[e], s);
  } else {
    s = whr[Vn + k];
  }
  wallb[j * Kc + k] = (unsigned short)f2b(s);
  if (k == 0) {
    float b = b_h[j];
    for (int e = 0; e < En; ++e) b = fmaf(b_in[e], whr[e], b);
    bc[j] = b;
  }
}

__global__ __launch_bounds__(128, 1) void rnn_fast2(
    const unsigned short* __restrict__ seqb, const unsigned short* __restrict__ wallb,
    const float* __restrict__ bc, const float* __restrict__ W_out,
    const float* __restrict__ b_out, float* __restrict__ out) {
  __shared__ __align__(16) unsigned char hbB[2][4096];

  const int tid = threadIdx.x;
  const int w   = tid >> 6;
  const int l   = tid & 63;
  const int l15 = l & 15;
  const int lg  = l >> 4;
  const int r0  = blockIdx.x * 16;
  const int swz = (l15 & 7) << 4;

  bf16x8 Aw[4][6];
  f32x4 bcv[4];
#pragma unroll
  for (int nn = 0; nn < 4; ++nn) {
    const int n = 4 * w + nn;
    const unsigned short* p = wallb + (size_t)(16 * n + l15) * Kc + lg * 8;
#pragma unroll
    for (int kt = 0; kt < 6; ++kt) Aw[nn][kt] = *(const bf16x8*)(p + kt * 32);
    bcv[nn] = *(const f32x4*)(bc + 16 * n + 4 * lg);
  }

  for (int i = tid; i < 2048; i += 128) ((unsigned int*)hbB)[i] = 0u;

  const unsigned short* sqb = seqb + ((size_t)(r0 + l15) * Ln) * Vn + lg * 8;
  bf16x8 sreg[4][2];

#define SEQ_PF(BI, T)                                                \
  { const int tp = ((T) < Ln) ? (T) : (Ln - 1);                      \
    const bf16x8* sp = (const bf16x8*)(sqb + (size_t)tp * Vn);       \
    sreg[BI][0] = sp[0];                                             \
    sreg[BI][1] = sp[4]; }

  SEQ_PF(0, 0)
  SEQ_PF(1, 1)
  SEQ_PF(2, 2)
  __syncthreads();

#define PHASE(P)                                                               \
  {                                                                            \
    const int cb = (P) & 1;                                                    \
    const unsigned char* zb = hbB[cb] + l15 * 256;                             \
    const bf16x8 z0 = *(const bf16x8*)(zb + ((16 * lg) ^ swz));                \
    const bf16x8 z1 = *(const bf16x8*)(zb + ((64 + 16 * lg) ^ swz));           \
    const bf16x8 z2 = *(const bf16x8*)(zb + ((128 + 16 * lg) ^ swz));          \
    const bf16x8 z3 = *(const bf16x8*)(zb + ((192 + 16 * lg) ^ swz));          \
    SEQ_PF(((P) + 3) & 3, t + (P) + 3);                                        \
    const bf16x8 s0 = sreg[(P)][0], s1 = sreg[(P)][1];                         \
    f32x4 p0 = bcv[0], p1 = bcv[1], p2 = bcv[2], p3 = bcv[3];                  \
    f32x4 q0 = {0.f, 0.f, 0.f, 0.f}, q1 = {0.f, 0.f, 0.f, 0.f};                \
    f32x4 q2 = {0.f, 0.f, 0.f, 0.f}, q3 = {0.f, 0.f, 0.f, 0.f};                \
    p0 = MFMA(Aw[0][0], s0, p0, 0, 0, 0);                                      \
    p1 = MFMA(Aw[1][0], s0, p1, 0, 0, 0);                                      \
    p2 = MFMA(Aw[2][0], s0, p2, 0, 0, 0);                                      \
    p3 = MFMA(Aw[3][0], s0, p3, 0, 0, 0);                                      \
    q0 = MFMA(Aw[0][1], s1, q0, 0, 0, 0);                                      \
    q1 = MFMA(Aw[1][1], s1, q1, 0, 0, 0);                                      \
    q2 = MFMA(Aw[2][1], s1, q2, 0, 0, 0);                                      \
    q3 = MFMA(Aw[3][1], s1, q3, 0, 0, 0);                                      \
    p0 = MFMA(Aw[0][2], z0, p0, 0, 0, 0);                                      \
    p1 = MFMA(Aw[1][2], z0, p1, 0, 0, 0);                                      \
    p2 = MFMA(Aw[2][2], z0, p2, 0, 0, 0);                                      \
    p3 = MFMA(Aw[3][2], z0, p3, 0, 0, 0);                                      \
    q0 = MFMA(Aw[0][3], z1, q0, 0, 0, 0);                                      \
    q1 = MFMA(Aw[1][3], z1, q1, 0, 0, 0);                                      \
    q2 = MFMA(Aw[2][3], z1, q2, 0, 0, 0);                                      \
    q3 = MFMA(Aw[3][3], z1, q3, 0, 0, 0);                                      \
    p0 = MFMA(Aw[0][4], z2, p0, 0, 0, 0);                                      \
    p1 = MFMA(Aw[1][4], z2, p1, 0, 0, 0);                                      \
    p2 = MFMA(Aw[2][4], z2, p2, 0, 0, 0);                                      \
    p3 = MFMA(Aw[3][4], z2, p3, 0, 0, 0);                                      \
    q0 = MFMA(Aw[0][5], z3, q0, 0, 0, 0);                                      \
    q1 = MFMA(Aw[1][5], z3, q1, 0, 0, 0);                                      \
    q2 = MFMA(Aw[2][5], z3, q2, 0, 0, 0);                                      \
    q3 = MFMA(Aw[3][5], z3, q3, 0, 0, 0);                                      \
    unsigned char* wbB = hbB[cb ^ 1] + l15 * 256;                              \
    _Pragma("unroll") for (int nn = 0; nn < 4; ++nn) {                         \
      const f32x4 pp = (nn == 0) ? p0 : (nn == 1) ? p1 : (nn == 2) ? p2 : p3;  \
      const f32x4 qq = (nn == 0) ? q0 : (nn == 1) ? q1 : (nn == 2) ? q2 : q3;  \
      const float r0v = fmaxf(pp[0] + qq[0], 0.f);                             \
      const float r1v = fmaxf(pp[1] + qq[1], 0.f);                             \
      const float r2v = fmaxf(pp[2] + qq[2], 0.f);                             \
      const float r3v = fmaxf(pp[3] + qq[3], 0.f);                             \
      unsigned d0, d1;                                                         \
      asm("v_cvt_pk_bf16_f32 %0, %1, %2" : "=v"(d0) : "v"(r0v), "v"(r1v));     \
      asm("v_cvt_pk_bf16_f32 %0, %1, %2" : "=v"(d1) : "v"(r2v), "v"(r3v));     \
      uint2 dd; dd.x = d0; dd.y = d1;                                          \
      *(uint2*)(wbB + ((128 * w + 32 * nn + 8 * lg) ^ swz)) = dd;              \
    }                                                                          \
    asm volatile("s_waitcnt lgkmcnt(0)" ::: "memory");                         \
    __builtin_amdgcn_s_barrier();                                              \
    asm volatile("" ::: "memory");                                             \
  }

#pragma unroll 1
  for (int t = 0; t < Ln; t += 4) {
    PHASE(0)
    PHASE(1)
    PHASE(2)
    PHASE(3)
  }
#undef PHASE
#undef SEQ_PF

  bf16x8 hz[4];
  const unsigned char* zb0 = hbB[0] + l15 * 256;
#pragma unroll
  for (int kt = 0; kt < 4; ++kt)
    hz[kt] = *(const bf16x8*)(zb0 + ((64 * kt + 16 * lg) ^ swz));
#pragma unroll
  for (int m = 0; m < 2; ++m) {
    const int v = 16 * (2 * w + m) + l15;
    const float* wor = W_out + (size_t)v * En + lg * 8;
    const float bo = b_out[v];
    f32x4 oa = {bo, bo, bo, bo};
#pragma unroll
    for (int kt = 0; kt < 4; ++kt) {
      float tmp[8];
      const float* p = wor + kt * 32;
#pragma unroll
      for (int i = 0; i < 8; ++i) tmp[i] = p[i];
      oa = MFMA(hz[kt], pack8(tmp), oa, 0, 0, 0);
    }
#pragma unroll
    for (int i = 0; i < 4; ++i)
      out[(size_t)(r0 + 4 * lg + i) * Vn + v] = oa[i];
  }
}

// ---------------- fp32 fallback (no workspace needed) ----------------

__global__ __launch_bounds__(256, 1) void rnn_mfma(
    const float* __restrict__ seq, const float* __restrict__ W_in,
    const float* __restrict__ b_in, const float* __restrict__ W_h,
    const float* __restrict__ b_h, const float* __restrict__ W_out,
    const float* __restrict__ b_out, float* __restrict__ out) {
  __shared__ __align__(16) unsigned short hb[2][16][136];

  const int tid = threadIdx.x;
  const int w   = tid >> 6;
  const int l   = tid & 63;
  const int l15 = l & 15;
  const int lg  = l >> 4;
  const int r0  = blockIdx.x * 16;

  bf16x8 Bw[2][6];
  float bc[2];
#pragma unroll
  for (int n = 0; n < 2; ++n) {
    const int j = 32 * w + 16 * n + l15;
    const float* whr = W_h + j * (2 * En);
    float b = b_h[j];
    for (int e = 0; e < En; ++e) b = fmaf(b_in[e], whr[e], b);
    bc[n] = b;
#pragma unroll
    for (int kt = 0; kt < 6; ++kt) {
      float v[8];
#pragma unroll
      for (int i = 0; i < 8; ++i) {
        const int k = kt * 32 + lg * 8 + i;
        if (k < Vn) {
          float s = 0.f;
          for (int e = 0; e < En; ++e) s = fmaf(W_in[e * Vn + k], whr[e], s);
          v[i] = s;
        } else {
          v[i] = whr[Vn + k];
        }
      }
      Bw[n][kt] = pack8(v);
    }
  }

  for (int i = tid; i < 2 * 16 * 136; i += 256) ((unsigned short*)hb)[i] = 0;

  const float* sq = seq + ((size_t)(r0 + l15) * Ln) * Vn + lg * 8;
  f32x4 sbuf[4][4];

#define SEQ_PF(BI, T)                                                 \
  { const int tp = ((T) < Ln) ? (T) : (Ln - 1);                       \
    const f32x4* p0 = (const f32x4*)(sq + (size_t)tp * Vn);           \
    const f32x4* p1 = (const f32x4*)(sq + (size_t)tp * Vn + 32);      \
    sbuf[BI][0] = p0[0]; sbuf[BI][1] = p0[1];                         \
    sbuf[BI][2] = p1[0]; sbuf[BI][3] = p1[1]; }

  SEQ_PF(0, 0)
  SEQ_PF(1, 1)
  SEQ_PF(2, 2)
  __syncthreads();

#define PHASE(P)                                                              \
  {                                                                           \
    const int cb = (P) & 1, nb = cb ^ 1;                                      \
    const bf16x8 h0 = *(const bf16x8*)&hb[cb][l15][lg * 8];                   \
    const bf16x8 h1 = *(const bf16x8*)&hb[cb][l15][32 + lg * 8];              \
    const bf16x8 h2 = *(const bf16x8*)&hb[cb][l15][64 + lg * 8];              \
    const bf16x8 h3 = *(const bf16x8*)&hb[cb][l15][96 + lg * 8];              \
    SEQ_PF(((P) + 3) & 3, t + (P) + 3);                                       \
    float v0[8], v1[8];                                                       \
    _Pragma("unroll") for (int i = 0; i < 4; ++i) {                           \
      v0[i] = sbuf[(P)][0][i]; v0[4 + i] = sbuf[(P)][1][i];                   \
      v1[i] = sbuf[(P)][2][i]; v1[4 + i] = sbuf[(P)][3][i];                   \
    }                                                                         \
    const bf16x8 a0 = pack8(v0), a1 = pack8(v1);                              \
    f32x4 p0a = {bc[0], bc[0], bc[0], bc[0]};                                 \
    f32x4 p1a = {bc[1], bc[1], bc[1], bc[1]};                                 \
    f32x4 q0a = {0.f, 0.f, 0.f, 0.f}, q1a = {0.f, 0.f, 0.f, 0.f};             \
    p0a = MFMA(a0, Bw[0][0], p0a, 0, 0, 0);                                   \
    p1a = MFMA(a0, Bw[1][0], p1a, 0, 0, 0);                                   \
    p0a = MFMA(a1, Bw[0][1], p0a, 0, 0, 0);                                   \
    p1a = MFMA(a1, Bw[1][1], p1a, 0, 0, 0);                                   \
    p0a = MFMA(h0, Bw[0][2], p0a, 0, 0, 0);                                   \
    p1a = MFMA(h0, Bw[1][2], p1a, 0, 0, 0);                                   \
    q0a = MFMA(h2, Bw[0][4], q0a, 0, 0, 0);                                   \
    q1a = MFMA(h2, Bw[1][4], q1a, 0, 0, 0);                                   \
    p0a = MFMA(h1, Bw[0][3], p0a, 0, 0, 0);                                   \
    p1a = MFMA(h1, Bw[1][3], p1a, 0, 0, 0);                                   \
    q0a = MFMA(h3, Bw[0][5], q0a, 0, 0, 0);                                   \
    q1a = MFMA(h3, Bw[1][5], q1a, 0, 0, 0);                                   \
    const int j0 = 32 * w + l15, j1 = j0 + 16, rr = 4 * lg;                   \
    _Pragma("unroll") for (int i = 0; i < 4; ++i) {                           \
      hb[nb][rr + i][j0] = (unsigned short)f2b(fmaxf(p0a[i] + q0a[i], 0.f));  \
      hb[nb][rr + i][j1] = (unsigned short)f2b(fmaxf(p1a[i] + q1a[i], 0.f));  \
    }                                                                         \
    asm volatile("s_waitcnt lgkmcnt(0)" ::: "memory");                        \
    __builtin_amdgcn_s_barrier();                                             \
    asm volatile("" ::: "memory");                                            \
  }

#pragma unroll 1
  for (int t = 0; t < Ln; t += 4) {
    PHASE(0)
    PHASE(1)
    PHASE(2)
    PHASE(3)
  }
#undef PHASE
#undef SEQ_PF

  const int orow = tid >> 4;
  const int oc   = (tid & 15) * 4;
  float o0 = b_out[oc], o1 = b_out[oc + 1], o2 = b_out[oc + 2], o3 = b_out[oc + 3];
  const float* w0 = W_out + (size_t)(oc + 0) * En;
  const float* w1 = W_out + (size_t)(oc + 1) * En;
  const float* w2 = W_out + (size_t)(oc + 2) * En;
  const float* w3 = W_out + (size_t)(oc + 3) * En;
#pragma unroll 8
  for (int k = 0; k < En; ++k) {
    const float hv = b2f(hb[0][orow][k]);
    o0 = fmaf(hv, w0[k], o0);
    o1 = fmaf(hv, w1[k], o1);
    o2 = fmaf(hv, w2[k], o2);
    o3 = fmaf(hv, w3[k], o3);
  }
  *(float4*)&out[(size_t)(r0 + orow) * Vn + oc] = make_float4(o0, o1, o2, o3);
}

extern "C" void kernel_launch(void* const* d_in, const int* in_sizes, int n_in,
                              void* d_out, int out_size, void* d_ws, size_t ws_size,
                              hipStream_t stream) {
  const float* seq   = (const float*)d_in[0];
  const float* W_in  = (const float*)d_in[1];
  const float* b_in  = (const float*)d_in[2];
  const float* W_h   = (const float*)d_in[3];
  const float* b_h   = (const float*)d_in[4];
  const float* W_out = (const float*)d_in[5];
  const float* b_out = (const float*)d_in[6];
  float* out = (float*)d_out;

  if (ws_size >= FAST_WS2) {
    unsigned short* seqb  = (unsigned short*)d_ws;
    unsigned short* wall2 = (unsigned short*)((char*)d_ws + SEQB_BYTES);
    float* bc             = (float*)((char*)d_ws + SEQB_BYTES + WALLB_BYTES);
    unsigned short* woutp = (unsigned short*)((char*)d_ws + SEQB_BYTES + WALLB_BYTES + BC_BYTES);
    seq_cvt<<<2048, 256, 0, stream>>>(seq, seqb);
    rnn_setup2<<<En, Kc, 0, stream>>>(W_in, b_in, W_h, b_h, wall2, bc);
    wout_setup<<<Vn, En, 0, stream>>>(W_out, woutp);
    rnn_grp8<<<Bn / 16, 512, 0, stream>>>(seqb, wall2, bc, woutp, b_out, out);
  } else if (ws_size >= FAST_WS) {
    unsigned short* seqb  = (unsigned short*)d_ws;
    unsigned short* wallb = (unsigned short*)((char*)d_ws + SEQB_BYTES);
    float* bc = (float*)((char*)d_ws + SEQB_BYTES + WALLB_BYTES);
    seq_cvt<<<2048, 256, 0, stream>>>(seq, seqb);
    rnn_setup_bf<<<En, Kc, 0, stream>>>(W_in, b_in, W_h, b_h, wallb, bc);
    rnn_fast2<<<Bn / 16, 128, 0, stream>>>(seqb, wallb, bc, W_out, b_out, out);
  } else {
    rnn_mfma<<<Bn / 16, 256, 0, stream>>>(seq, W_in, b_in, W_h, b_h, W_out, b_out, out);
  }
}